// Round 18
// baseline (151.545 us; speedup 1.0000x reference)
//
#include <hip/hip_runtime.h>

// MyHingeLoss: cosine hinge loss, N=32768, D=512, fp32. Floor ~21 us.
// R16 evidence: harness's own fillBuffer hits 6.58 TB/s (82% peak) on this
// machine -> floor is NOT external. hinge at 41us: VALU 34%, BW 20%, occ
// 64%, no conflicts -> wave-LIFETIME latency bound: each wave loads 1 row,
// stalls ~900cy, computes ~300cy, dies (32 slots x ~3000cy == 41us). R17:
// persistent 2048 blocks, 4 rows/wave, PREFETCH row i+1's loads before
// reducing row i (ILP across rows); t5+tn5 register-resident per wave
// (10 fewer loads/row; L2 t5 traffic 327->82 MB). VGPR ~95 -> 4 w/SIMD,
// but every wave keeps 4KB in flight under compute.

constexpr int D   = 512;           // floats per row (128 float4)
constexpr int NC  = 5;             // NUM_COMPARE
constexpr float MARGIN_F = 0.1f;
constexpr float EPS_F    = 1e-6f;

__device__ __forceinline__ float dot4(const float4 a, const float4 b) {
  return a.x*b.x + a.y*b.y + a.z*b.z + a.w*b.w;
}

template <int CTRL>
__device__ __forceinline__ float dpp_add(float x) {
  const int y = __builtin_amdgcn_update_dpp(
      0, __float_as_int(x), CTRL, 0xF, 0xF, true);
  return x + __int_as_float(y);
}

// Full 64-lane sum, replicated in all lanes. 4 VALU-pipe DPP steps
// (quad_perm xor1=0xB1, xor2=0x4E, row_ror:4=0x124, row_ror:8=0x128)
// + 2 cross-row shuffles.
__device__ __forceinline__ float red64(float x) {
  x = dpp_add<0xB1>(x);
  x = dpp_add<0x4E>(x);
  x = dpp_add<0x124>(x);
  x = dpp_add<0x128>(x);
  x += __shfl_xor(x, 16);
  x += __shfl_xor(x, 32);
  return x;
}

// Pre-kernel: tn5[j] = ||target[j]||, one wave per row, 1 block.
__global__ __launch_bounds__(320) void tn5_kernel(
    const float* __restrict__ tgt, float* __restrict__ tn5_out)
{
  const int w = threadIdx.x >> 6, lane = threadIdx.x & 63;
  const float4* tp = reinterpret_cast<const float4*>(tgt) + w * 128;
  const float4 a = tp[lane], b = tp[64 + lane];
  const float s = red64(dot4(a, a) + dot4(b, b));
  if (lane == 0) tn5_out[w] = sqrtf(s);
}

// Persistent: 2048 blocks x 4 waves = 8192 waves, 4 rows each, software-
// pipelined: next row's 4 loads issued BEFORE current row's reduction.
__global__ __launch_bounds__(256) void hinge_kernel(
    const float* __restrict__ out, const float* __restrict__ tgt,
    const float* __restrict__ tn5g, float* __restrict__ partial, int n)
{
  const int tid  = threadIdx.x;
  const int wid  = tid >> 6;
  const int lane = tid & 63;
  const int gwave = blockIdx.x * 4 + wid;            // 0..8191
  const int nw    = gridDim.x * 4;                   // 8192
  const int rpw   = (n + nw - 1) / nw;               // 4

  const float4* op  = reinterpret_cast<const float4*>(out);
  const float4* tp  = reinterpret_cast<const float4*>(tgt);

  // t5 + tn5 register-resident (invariant across this wave's 4 rows).
  float4 t5r[NC][2];
  #pragma unroll
  for (int j = 0; j < NC; ++j) {
    t5r[j][0] = tp[j * 128 + lane];
    t5r[j][1] = tp[j * 128 + 64 + lane];
  }
  float tn5[NC];
  #pragma unroll
  for (int j = 0; j < NC; ++j) tn5[j] = tn5g[j];     // uniform -> s_loads

  const int row0 = gwave * rpw;

  // Prologue: loads for row0.
  float4 co0, co1, ct0, ct1;
  {
    const size_t r = (size_t)min(row0, n - 1) * 128;
    co0 = op[r + lane];  co1 = op[r + 64 + lane];
    ct0 = tp[r + lane];  ct1 = tp[r + 64 + lane];
  }

  float acc = 0.f;
  #pragma unroll
  for (int it = 0; it < 4; ++it) {
    // Prefetch next row (independent of current compute -> stays in flight).
    float4 no0, no1, nt0, nt1;
    if (it < 3) {
      const size_t r = (size_t)min(row0 + it + 1, n - 1) * 128;
      no0 = op[r + lane];  no1 = op[r + 64 + lane];
      nt0 = tp[r + lane];  nt1 = tp[r + 64 + lane];
    }

    // Current row: 8 dots from registers.
    float s_ot = dot4(co0, ct0) + dot4(co1, ct1);
    float s_oo = dot4(co0, co0) + dot4(co1, co1);
    float s_tt = dot4(ct0, ct0) + dot4(ct1, ct1);
    float s5[NC];
    #pragma unroll
    for (int j = 0; j < NC; ++j)
      s5[j] = dot4(co0, t5r[j][0]) + dot4(co1, t5r[j][1]);

    s_ot = red64(s_ot);
    s_oo = red64(s_oo);
    s_tt = red64(s_tt);
    #pragma unroll
    for (int j = 0; j < NC; ++j) s5[j] = red64(s5[j]);

    const int row = row0 + it;
    if (row < n) {                       // uniform per wave; no lane branch
      const float on  = sqrtf(s_oo);
      const float tn  = sqrtf(s_tt);
      const float pos = s_ot / fmaxf(on * tn, EPS_F);
      #pragma unroll
      for (int j = 0; j < NC; ++j) {
        const float S = s5[j] / fmaxf(on * tn5[j], EPS_F);
        const float hv = fmaxf(0.f, MARGIN_F - pos + S);
        acc += (row == j) ? 0.f : hv;    // acc replicated in all lanes
      }
    }
    co0 = no0; co1 = no1; ct0 = nt0; ct1 = nt1;
  }

  __shared__ float bsum[4];
  if (lane == 0) bsum[wid] = acc;
  __syncthreads();
  if (tid == 0) partial[blockIdx.x] = bsum[0] + bsum[1] + bsum[2] + bsum[3];
}

__global__ __launch_bounds__(256) void reduce_kernel(
    const float* __restrict__ part, float* __restrict__ result,
    int nw, float inv_count)
{
  float s = 0.f;
  for (int i = threadIdx.x; i < nw; i += 256) s += part[i];
  s = red64(s);
  __shared__ float ws[4];
  if ((threadIdx.x & 63) == 0) ws[threadIdx.x >> 6] = s;
  __syncthreads();
  if (threadIdx.x == 0) result[0] = (ws[0] + ws[1] + ws[2] + ws[3]) * inv_count;
}

extern "C" void kernel_launch(void* const* d_in, const int* in_sizes, int n_in,
                              void* d_out, int out_size, void* d_ws, size_t ws_size,
                              hipStream_t stream) {
  const float* out = (const float*)d_in[0];
  const float* tgt = (const float*)d_in[1];
  float* result   = (float*)d_out;
  float* partials = (float*)d_ws;            // [0 .. 2047]
  float* tn5_ws   = partials + 2048;         // [2048 .. 2052]

  const int n = in_sizes[0] / D;             // 32768
  const int blocks = 2048;                   // persistent: 8192 waves x 4 rows
  const long long count = (long long)n * NC - (n < NC ? n : NC);
  const float inv_count = 1.0f / (float)count;

  tn5_kernel<<<1, 320, 0, stream>>>(tgt, tn5_ws);
  hinge_kernel<<<blocks, 256, 0, stream>>>(out, tgt, tn5_ws, partials, n);
  reduce_kernel<<<1, 256, 0, stream>>>(partials, result, blocks, inv_count);
}